// Round 5
// baseline (656.652 us; speedup 1.0000x reference)
//
#include <hip/hip_runtime.h>

#define D 64
#define BK_SHIFT 6              // 64 nodes per bucket
#define BK_CAP 8192             // staged entries per bucket (mean ~1600)

__device__ __forceinline__ float bfbits2f(unsigned short b) {
    union { unsigned int u; float f; } c;
    c.u = ((unsigned int)b) << 16;
    return c.f;
}

__device__ __forceinline__ unsigned short f2bfbits(float f) {
    union { float f; unsigned int u; } c;
    c.f = f;
    unsigned int u = c.u;
    unsigned int lsb = (u >> 16) & 1u;
    u += 0x7fffu + lsb;           // round-to-nearest-even
    return (unsigned short)(u >> 16);
}

__device__ __forceinline__ float ldmix(const void* p, size_t i, int isf32) {
    return isf32 ? ((const float*)p)[i] : bfbits2f(((const unsigned short*)p)[i]);
}

// ---- dtype sniff -----------------------------------------------------------
__global__ void sniff_kernel(const unsigned short* __restrict__ W, int* __restrict__ flag) {
    int t = threadIdx.x;
    bool bad = false;
    for (int i = t; i < 256; i += 64) {
        float v = bfbits2f(W[i]);
        if (!(v == v) || fabsf(v) > 1e4f) bad = true;
    }
    unsigned long long m = __ballot(bad);
    if (t == 0) *flag = (m != 0ull) ? 1 : 0;
}

// ---- param conversion ------------------------------------------------------
#define OW1 0
#define OW2 4096
#define OW3 8192
#define OB1 12288
#define OB2 12352
#define OB3 12416
#define OG  12480
#define OBE 12544
#define OPA 12608

__global__ void cvt_params_kernel(const void* W1, const void* b1, const void* W2, const void* b2,
                                  const void* W3, const void* b3, const void* pa, const void* g,
                                  const void* be, const int* __restrict__ flag,
                                  float* __restrict__ P) {
    int isf = *flag;
    int t = threadIdx.x;                 // one block of 256
    for (int i = t; i < D * D; i += 256) {
        P[OW1 + i] = ldmix(W1, i, isf);
        P[OW2 + i] = ldmix(W2, i, isf);
        P[OW3 + i] = ldmix(W3, i, isf);
    }
    if (t < D) {
        P[OB1 + t] = ldmix(b1, t, isf);
        P[OB2 + t] = ldmix(b2, t, isf);
        P[OB3 + t] = ldmix(b3, t, isf);
        P[OG  + t] = ldmix(g,  t, isf);
        P[OBE + t] = ldmix(be, t, isf);
    }
    if (t == 0) P[OPA] = ldmix(pa, 0, isf);
}

// ---- bucketed CSR build ----------------------------------------------------
// buckets of 64 consecutive dst nodes; NB = ceil(N/64) <= 1024

__global__ void bucket_hist_kernel(const int* __restrict__ dst, int E, int NB,
                                   int* __restrict__ bhist) {
    __shared__ int h[1024];
    int t = threadIdx.x;
    for (int i = t; i < NB; i += 256) h[i] = 0;
    __syncthreads();
    for (int e = blockIdx.x * 256 + t; e < E; e += gridDim.x * 256)
        atomicAdd(&h[dst[e] >> BK_SHIFT], 1);
    __syncthreads();
    for (int i = t; i < NB; i += 256) { int v = h[i]; if (v) atomicAdd(&bhist[i], v); }
}

// single block, 1024 threads: ordered scan of bucket counts
__global__ void bucket_scan_kernel(const int* __restrict__ bhist, int* __restrict__ bucket_beg,
                                   int* __restrict__ bcur, int NB) {
    __shared__ int tile[1024];
    int t = threadIdx.x;
    int v = (t < NB) ? bhist[t] : 0;
    tile[t] = v;
    __syncthreads();
    for (int off = 1; off < 1024; off <<= 1) {
        int add = (t >= off) ? tile[t - off] : 0;
        __syncthreads();
        tile[t] += add;
        __syncthreads();
    }
    if (t < NB) { int beg = tile[t] - v; bucket_beg[t] = beg; bcur[t] = beg; }
    if (t == NB - 1) bucket_beg[NB] = tile[t];
}

// append packed (src<<6 | dst&63) into bucket region (contiguous tail appends)
__global__ void binA_kernel(const int* __restrict__ src, const int* __restrict__ dst,
                            int* __restrict__ bcur, unsigned int* __restrict__ tmp, int E) {
    int e = blockIdx.x * 256 + threadIdx.x;
    if (e < E) {
        int d = dst[e];
        int p = atomicAdd(&bcur[d >> BK_SHIFT], 1);
        tmp[p] = ((unsigned int)src[e] << BK_SHIFT) | (unsigned int)(d & 63);
    }
}

// one block per bucket: local count + scan + L2-local scatter; emits row_beg/cnt/dinv/col
__global__ void binB_kernel(const unsigned int* __restrict__ tmp, const int* __restrict__ bucket_beg,
                            int* __restrict__ row_beg, int* __restrict__ cnt,
                            float* __restrict__ dinv, int* __restrict__ col, int N) {
    __shared__ unsigned int ent[BK_CAP];
    __shared__ int lcnt[64], lcur[64];
    int b = blockIdx.x, t = threadIdx.x;
    int beg = bucket_beg[b], end = bucket_beg[b + 1];
    int m = end - beg;
    bool staged = (m <= BK_CAP);
    if (t < 64) lcnt[t] = 0;
    __syncthreads();
    for (int i = t; i < m; i += 256) {
        unsigned int e = tmp[beg + i];
        if (staged) ent[i] = e;
        atomicAdd(&lcnt[e & 63u], 1);
    }
    __syncthreads();
    if (t < 64) {
        int v = lcnt[t];
        int incl = v;
#pragma unroll
        for (int off = 1; off < 64; off <<= 1) {
            int u = __shfl_up(incl, off, 64);
            if (t >= off) incl += u;
        }
        int excl = incl - v;
        lcur[t] = excl;
        int node = b * 64 + t;
        if (node < N) {
            row_beg[node] = beg + excl;
            cnt[node]     = v;
            dinv[node]    = rsqrtf((float)(v + 1));
        }
    }
    __syncthreads();
    for (int i = t; i < m; i += 256) {
        unsigned int e = staged ? ent[i] : tmp[beg + i];
        int p = atomicAdd(&lcur[e & 63u], 1);
        col[beg + p] = (int)(e >> BK_SHIFT);
    }
}

// ---- feature kernels -------------------------------------------------------

__global__ void prescale_kernel(const void* __restrict__ X, const float* __restrict__ dinv,
                                const int* __restrict__ flag, unsigned short* __restrict__ Xs, int n) {
    int isf = *flag;
    int gid  = blockIdx.x * blockDim.x + threadIdx.x;
    int node = gid >> 6;
    if (node >= n) return;
    Xs[gid] = f2bfbits(dinv[node] * ldmix(X, (size_t)gid, isf));
}

// acc = dinv[node] * ( Xs[node] + sum_neighbors Xs[s] )   (per lane)
__device__ __forceinline__ float aggregate(const unsigned short* __restrict__ Xs,
                                           const int* __restrict__ row_beg,
                                           const int* __restrict__ cnt,
                                           const int* __restrict__ col,
                                           const float* __restrict__ dinv,
                                           int node, int lane) {
    float a0 = bfbits2f(Xs[(size_t)node * D + lane]);    // self loop
    float a1 = 0.f, a2 = 0.f, a3 = 0.f;
    float a4 = 0.f, a5 = 0.f, a6 = 0.f, a7 = 0.f;
    int beg = row_beg[node], m_tot = cnt[node];
    for (int chunk = 0; chunk < m_tot; chunk += 64) {
        int m = m_tot - chunk; if (m > 64) m = 64;
        int idx = (lane < m) ? col[beg + chunk + lane] : 0;
        int i = 0;
        for (; i + 7 < m; i += 8) {                      // 8 loads in flight
            int s0 = __shfl(idx, i,     64);
            int s1 = __shfl(idx, i + 1, 64);
            int s2 = __shfl(idx, i + 2, 64);
            int s3 = __shfl(idx, i + 3, 64);
            int s4 = __shfl(idx, i + 4, 64);
            int s5 = __shfl(idx, i + 5, 64);
            int s6 = __shfl(idx, i + 6, 64);
            int s7 = __shfl(idx, i + 7, 64);
            a0 += bfbits2f(Xs[(size_t)s0 * D + lane]);
            a1 += bfbits2f(Xs[(size_t)s1 * D + lane]);
            a2 += bfbits2f(Xs[(size_t)s2 * D + lane]);
            a3 += bfbits2f(Xs[(size_t)s3 * D + lane]);
            a4 += bfbits2f(Xs[(size_t)s4 * D + lane]);
            a5 += bfbits2f(Xs[(size_t)s5 * D + lane]);
            a6 += bfbits2f(Xs[(size_t)s6 * D + lane]);
            a7 += bfbits2f(Xs[(size_t)s7 * D + lane]);
        }
        for (; i < m; ++i) {
            int s0 = __shfl(idx, i, 64);
            a0 += bfbits2f(Xs[(size_t)s0 * D + lane]);
        }
    }
    return dinv[node] * (((a0 + a1) + (a2 + a3)) + ((a4 + a5) + (a6 + a7)));
}

__global__ void agg_gemm_kernel(const unsigned short* __restrict__ Xs,
                                const int* __restrict__ row_beg, const int* __restrict__ cnt,
                                const int* __restrict__ col, const float* __restrict__ dinv,
                                const float* __restrict__ W, const float* __restrict__ b,
                                const float* __restrict__ pa,
                                unsigned short* __restrict__ Xout, int n) {
    __shared__ float Wl[D * D];
    int t = threadIdx.x;
    for (int i = t; i < D * D; i += 256) Wl[i] = W[i];
    __syncthreads();
    int node = blockIdx.x * 4 + (t >> 6);
    int lane = t & 63;
    if (node >= n) return;
    float xr = aggregate(Xs, row_beg, cnt, col, dinv, node, lane);
    float acc = 0.f;
#pragma unroll
    for (int k = 0; k < D; ++k) {
        float xv = __shfl(xr, k, 64);
        acc = fmaf(xv, Wl[k * D + lane], acc);
    }
    acc += b[lane];
    float a = pa[0];
    acc = (acc >= 0.f) ? acc : a * acc;
    acc *= dinv[node];                            // prescale for next layer's aggregation
    Xout[(size_t)node * D + lane] = f2bfbits(acc);
}

__global__ void agg_gemm_ln_kernel(const unsigned short* __restrict__ Xs,
                                   const int* __restrict__ row_beg, const int* __restrict__ cnt,
                                   const int* __restrict__ col, const float* __restrict__ dinv,
                                   const float* __restrict__ W, const float* __restrict__ b,
                                   const float* __restrict__ g, const float* __restrict__ be,
                                   const int* __restrict__ flag, void* __restrict__ out, int n) {
    __shared__ float Wl[D * D];
    int t = threadIdx.x;
    for (int i = t; i < D * D; i += 256) Wl[i] = W[i];
    __syncthreads();
    int node = blockIdx.x * 4 + (t >> 6);
    int lane = t & 63;
    if (node >= n) return;
    float xr = aggregate(Xs, row_beg, cnt, col, dinv, node, lane);
    float acc = 0.f;
#pragma unroll
    for (int k = 0; k < D; ++k) {
        float xv = __shfl(xr, k, 64);
        acc = fmaf(xv, Wl[k * D + lane], acc);
    }
    acc += b[lane];
    float s = acc;
#pragma unroll
    for (int off = 32; off > 0; off >>= 1) s += __shfl_xor(s, off, 64);
    float mu  = s * (1.f / 64.f);
    float dfe = acc - mu;
    float v   = dfe * dfe;
#pragma unroll
    for (int off = 32; off > 0; off >>= 1) v += __shfl_xor(v, off, 64);
    float var = v * (1.f / 64.f);
    float r   = rsqrtf(var + 1e-5f);
    float o   = dfe * r * g[lane] + be[lane];
    size_t oi = (size_t)node * D + lane;
    if (*flag) ((float*)out)[oi] = o;
    else       ((unsigned short*)out)[oi] = f2bfbits(o);
}

// ---- driver ----------------------------------------------------------------

extern "C" void kernel_launch(void* const* d_in, const int* in_sizes, int n_in,
                              void* d_out, int out_size, void* d_ws, size_t ws_size,
                              hipStream_t stream) {
    const void* X   = d_in[0];
    const void* W1  = d_in[1];
    const void* b1  = d_in[2];
    const void* W2  = d_in[3];
    const void* b2  = d_in[4];
    const void* W3  = d_in[5];
    const void* b3  = d_in[6];
    const void* pa  = d_in[7];
    const void* g   = d_in[8];
    const void* be  = d_in[9];
    const int*  ei  = (const int*)d_in[10];

    int N = in_sizes[0] / D;
    int E = in_sizes[10] / 2;
    int NB = (N + 63) >> BK_SHIFT;   // <= 1024 for N <= 65536
    const int* src = ei;
    const int* dst = ei + E;

    char* p = (char*)d_ws;
    auto alloc = [&](size_t bytes) { void* q = (void*)p; p += (bytes + 255) & ~(size_t)255; return q; };
    int*            flag       = (int*)alloc(4);
    int*            bhist      = (int*)alloc(1024 * 4);
    int*            bucket_beg = (int*)alloc(1025 * 4);
    int*            bcur       = (int*)alloc(1024 * 4);
    int*            row_beg    = (int*)alloc((size_t)N * 4);
    int*            cnt        = (int*)alloc((size_t)N * 4);
    float*          dinv       = (float*)alloc((size_t)N * 4);
    int*            col        = (int*)alloc((size_t)E * 4);
    unsigned int*   tmp        = (unsigned int*)alloc((size_t)E * 4);
    float*          P          = (float*)alloc((size_t)(OPA + 1) * 4);
    unsigned short* Xs         = (unsigned short*)alloc((size_t)N * D * 2);
    unsigned short* Xs2        = (unsigned short*)alloc((size_t)N * D * 2);
    (void)ws_size; (void)n_in; (void)out_size;

    (void)hipMemsetAsync(bhist, 0, 1024 * 4, stream);

    sniff_kernel<<<1, 64, 0, stream>>>((const unsigned short*)W1, flag);
    cvt_params_kernel<<<1, 256, 0, stream>>>(W1, b1, W2, b2, W3, b3, pa, g, be, flag, P);

    int eb = (E + 255) / 256;
    bucket_hist_kernel<<<256, 256, 0, stream>>>(dst, E, NB, bhist);
    bucket_scan_kernel<<<1, 1024, 0, stream>>>(bhist, bucket_beg, bcur, NB);
    binA_kernel<<<eb, 256, 0, stream>>>(src, dst, bcur, tmp, E);
    binB_kernel<<<NB, 256, 0, stream>>>(tmp, bucket_beg, row_beg, cnt, dinv, col, N);

    int nwb = (N * D + 255) / 256;   // one wave per node
    int ngb = (N + 3) / 4;           // 4 nodes per 256-thread block

    prescale_kernel<<<nwb, 256, 0, stream>>>(X, dinv, flag, Xs, N);

    agg_gemm_kernel   <<<ngb, 256, 0, stream>>>(Xs,  row_beg, cnt, col, dinv, P + OW1, P + OB1, P + OPA, Xs2, N);
    agg_gemm_kernel   <<<ngb, 256, 0, stream>>>(Xs2, row_beg, cnt, col, dinv, P + OW2, P + OB2, P + OPA, Xs,  N);
    agg_gemm_ln_kernel<<<ngb, 256, 0, stream>>>(Xs,  row_beg, cnt, col, dinv, P + OW3, P + OB3, P + OG, P + OBE, flag, d_out, N);
}

// Round 6
// 372.954 us; speedup vs baseline: 1.7607x; 1.7607x over previous
//
#include <hip/hip_runtime.h>

#define D 64
#define BK_SHIFT 6              // 64 nodes per bucket
#define BK_CAP 8192             // staged entries per bucket (mean ~1600)
#define NBLK 256                // radix pass blocks

__device__ __forceinline__ float bfbits2f(unsigned short b) {
    union { unsigned int u; float f; } c;
    c.u = ((unsigned int)b) << 16;
    return c.f;
}

__device__ __forceinline__ unsigned short f2bfbits(float f) {
    union { float f; unsigned int u; } c;
    c.f = f;
    unsigned int u = c.u;
    unsigned int lsb = (u >> 16) & 1u;
    u += 0x7fffu + lsb;           // round-to-nearest-even
    return (unsigned short)(u >> 16);
}

__device__ __forceinline__ float ldmix(const void* p, size_t i, int isf32) {
    return isf32 ? ((const float*)p)[i] : bfbits2f(((const unsigned short*)p)[i]);
}

// ---- dtype sniff -----------------------------------------------------------
__global__ void sniff_kernel(const unsigned short* __restrict__ W, int* __restrict__ flag) {
    int t = threadIdx.x;
    bool bad = false;
    for (int i = t; i < 256; i += 64) {
        float v = bfbits2f(W[i]);
        if (!(v == v) || fabsf(v) > 1e4f) bad = true;
    }
    unsigned long long m = __ballot(bad);
    if (t == 0) *flag = (m != 0ull) ? 1 : 0;
}

// ---- param conversion ------------------------------------------------------
#define OW1 0
#define OW2 4096
#define OW3 8192
#define OB1 12288
#define OB2 12352
#define OB3 12416
#define OG  12480
#define OBE 12544
#define OPA 12608

__global__ void cvt_params_kernel(const void* W1, const void* b1, const void* W2, const void* b2,
                                  const void* W3, const void* b3, const void* pa, const void* g,
                                  const void* be, const int* __restrict__ flag,
                                  float* __restrict__ P) {
    int isf = *flag;
    int t = threadIdx.x;                 // one block of 256
    for (int i = t; i < D * D; i += 256) {
        P[OW1 + i] = ldmix(W1, i, isf);
        P[OW2 + i] = ldmix(W2, i, isf);
        P[OW3 + i] = ldmix(W3, i, isf);
    }
    if (t < D) {
        P[OB1 + t] = ldmix(b1, t, isf);
        P[OB2 + t] = ldmix(b2, t, isf);
        P[OB3 + t] = ldmix(b3, t, isf);
        P[OG  + t] = ldmix(g,  t, isf);
        P[OBE + t] = ldmix(be, t, isf);
    }
    if (t == 0) P[OPA] = ldmix(pa, 0, isf);
}

// ---- deterministic two-pass radix binning (no global atomics) --------------
// H layout: H[bucket * NBLK + block]

__global__ void binA1_kernel(const int* __restrict__ dst, int E, int NB, int CH,
                             int* __restrict__ H) {
    __shared__ int h[1024];
    int t = threadIdx.x, bb = blockIdx.x;
    for (int i = t; i < NB; i += 256) h[i] = 0;
    __syncthreads();
    int beg = bb * CH, end = beg + CH; if (end > E) end = E;
    for (int e = beg + t; e < end; e += 256)
        atomicAdd(&h[dst[e] >> BK_SHIFT], 1);
    __syncthreads();
    for (int i = t; i < NB; i += 256) H[i * NBLK + bb] = h[i];
}

// per-bucket exclusive scan of the NBLK block-counts; T[b] = bucket total
__global__ void binA2_kernel(int* __restrict__ H, int* __restrict__ T) {
    __shared__ int ws[4];
    __shared__ int wx[4];
    int b = blockIdx.x, t = threadIdx.x;
    int lane = t & 63, wid = t >> 6;
    int v = H[b * NBLK + t];
    int incl = v;
#pragma unroll
    for (int off = 1; off < 64; off <<= 1) {
        int u = __shfl_up(incl, off, 64);
        if (lane >= off) incl += u;
    }
    if (lane == 63) ws[wid] = incl;
    __syncthreads();
    if (t == 0) {
        int s = 0;
#pragma unroll
        for (int j = 0; j < 4; ++j) { wx[j] = s; s += ws[j]; }
        T[b] = s;
    }
    __syncthreads();
    H[b * NBLK + t] = wx[wid] + incl - v;
}

// single-block scan of bucket totals -> bucket_beg
__global__ void binA3_kernel(const int* __restrict__ T, int* __restrict__ bucket_beg, int NB) {
    __shared__ int tile[1024];
    int t = threadIdx.x;
    int v = (t < NB) ? T[t] : 0;
    tile[t] = v;
    __syncthreads();
    for (int off = 1; off < 1024; off <<= 1) {
        int add = (t >= off) ? tile[t - off] : 0;
        __syncthreads();
        tile[t] += add;
        __syncthreads();
    }
    if (t < NB) bucket_beg[t] = tile[t] - v;
    if (t == NB - 1) bucket_beg[NB] = tile[t];
}

// scatter edges into bucket-grouped tmp via LDS cursors (deterministic ranges)
__global__ void binA4_kernel(const int* __restrict__ src, const int* __restrict__ dst,
                             const int* __restrict__ H, const int* __restrict__ bucket_beg,
                             unsigned int* __restrict__ tmp, int E, int NB, int CH) {
    __shared__ int O[1024];
    int t = threadIdx.x, bb = blockIdx.x;
    for (int i = t; i < NB; i += 256) O[i] = bucket_beg[i] + H[i * NBLK + bb];
    __syncthreads();
    int beg = bb * CH, end = beg + CH; if (end > E) end = E;
    for (int e = beg + t; e < end; e += 256) {
        int d = dst[e];
        int p = atomicAdd(&O[d >> BK_SHIFT], 1);
        tmp[p] = ((unsigned int)src[e] << BK_SHIFT) | (unsigned int)(d & 63);
    }
}

// one block per bucket: per-node count + scan + L2-local scatter
__global__ void binB_kernel(const unsigned int* __restrict__ tmp, const int* __restrict__ bucket_beg,
                            int* __restrict__ row_beg, int* __restrict__ cnt,
                            float* __restrict__ dinv, int* __restrict__ col, int N) {
    __shared__ unsigned int ent[BK_CAP];
    __shared__ int lcnt[64], lcur[64];
    int b = blockIdx.x, t = threadIdx.x;
    int beg = bucket_beg[b], end = bucket_beg[b + 1];
    int m = end - beg;
    bool staged = (m <= BK_CAP);
    if (t < 64) lcnt[t] = 0;
    __syncthreads();
    for (int i = t; i < m; i += 256) {
        unsigned int e = tmp[beg + i];
        if (staged) ent[i] = e;
        atomicAdd(&lcnt[e & 63u], 1);
    }
    __syncthreads();
    if (t < 64) {
        int v = lcnt[t];
        int incl = v;
#pragma unroll
        for (int off = 1; off < 64; off <<= 1) {
            int u = __shfl_up(incl, off, 64);
            if (t >= off) incl += u;
        }
        int excl = incl - v;
        lcur[t] = excl;
        int node = b * 64 + t;
        if (node < N) {
            row_beg[node] = beg + excl;
            cnt[node]     = v;
            dinv[node]    = rsqrtf((float)(v + 1));
        }
    }
    __syncthreads();
    for (int i = t; i < m; i += 256) {
        unsigned int e = staged ? ent[i] : tmp[beg + i];
        int p = atomicAdd(&lcur[e & 63u], 1);
        col[beg + p] = (int)(e >> BK_SHIFT);
    }
}

// ---- feature kernels -------------------------------------------------------

__global__ void prescale_kernel(const void* __restrict__ X, const float* __restrict__ dinv,
                                const int* __restrict__ flag, unsigned short* __restrict__ Xs, int n) {
    int isf = *flag;
    int gid  = blockIdx.x * blockDim.x + threadIdx.x;
    int node = gid >> 6;
    if (node >= n) return;
    Xs[gid] = f2bfbits(dinv[node] * ldmix(X, (size_t)gid, isf));
}

__device__ __forceinline__ void acc8(float* a, uint4 v) {
    a[0] += bfbits2f((unsigned short)(v.x & 0xffffu));
    a[1] += bfbits2f((unsigned short)(v.x >> 16));
    a[2] += bfbits2f((unsigned short)(v.y & 0xffffu));
    a[3] += bfbits2f((unsigned short)(v.y >> 16));
    a[4] += bfbits2f((unsigned short)(v.z & 0xffffu));
    a[5] += bfbits2f((unsigned short)(v.z >> 16));
    a[6] += bfbits2f((unsigned short)(v.w & 0xffffu));
    a[7] += bfbits2f((unsigned short)(v.w >> 16));
}

// vectorized gather: wave covers 8 source rows per load (slot=lane>>3 picks row,
// sub=lane&7 picks the 16B chunk). x8[j] = aggregated feature (lane&7)*8+j.
__device__ __forceinline__ void aggregate8(const unsigned short* __restrict__ Xs,
                                           const int* __restrict__ row_beg,
                                           const int* __restrict__ cnt,
                                           const int* __restrict__ col,
                                           const float* __restrict__ dinv,
                                           int node, int lane, float* __restrict__ x8) {
    const int slot = lane >> 3;
    const int sub  = lane & 7;
    float a[8];
#pragma unroll
    for (int j = 0; j < 8; ++j) a[j] = 0.f;
    int beg = row_beg[node], m_tot = cnt[node];
    for (int chunk = 0; chunk < m_tot; chunk += 64) {
        int m = m_tot - chunk; if (m > 64) m = 64;
        int idx = (lane < m) ? col[beg + chunk + lane] : 0;
        for (int i = 0; i < m; i += 8) {
            int r = i + slot;                                   // r <= 63
            int s = __shfl(idx, r, 64);                         // r>=m -> node 0 (safe addr)
            uint4 v = *((const uint4*)(Xs + ((size_t)s << 6)) + sub);
            if (r < m) acc8(a, v);                              // mask tail rows
        }
    }
    // reduce the 8 row-slots (flip lane bits 3..5; sub preserved)
#pragma unroll
    for (int off = 8; off < 64; off <<= 1) {
#pragma unroll
        for (int j = 0; j < 8; ++j) a[j] += __shfl_xor(a[j], off, 64);
    }
    // self loop
    uint4 sv = *((const uint4*)(Xs + ((size_t)node << 6)) + sub);
    acc8(a, sv);
    float dn = dinv[node];
#pragma unroll
    for (int j = 0; j < 8; ++j) x8[j] = dn * a[j];
}

__global__ void agg_gemm_kernel(const unsigned short* __restrict__ Xs,
                                const int* __restrict__ row_beg, const int* __restrict__ cnt,
                                const int* __restrict__ col, const float* __restrict__ dinv,
                                const float* __restrict__ W, const float* __restrict__ b,
                                const float* __restrict__ pa,
                                unsigned short* __restrict__ Xout, int n) {
    __shared__ float Wl[D * D];
    int t = threadIdx.x;
    for (int i = t; i < D * D; i += 256) Wl[i] = W[i];
    __syncthreads();
    int node = blockIdx.x * 4 + (t >> 6);
    int lane = t & 63;
    if (node >= n) return;
    float x8[8];
    aggregate8(Xs, row_beg, cnt, col, dinv, node, lane, x8);
    float acc = 0.f;
#pragma unroll
    for (int k = 0; k < D; ++k) {
        float xv = __shfl(x8[k & 7], k >> 3, 64);   // feature k lives in lane k>>3, elem k&7
        acc = fmaf(xv, Wl[k * D + lane], acc);
    }
    acc += b[lane];
    float a = pa[0];
    acc = (acc >= 0.f) ? acc : a * acc;
    acc *= dinv[node];                              // prescale for next layer
    Xout[(size_t)node * D + lane] = f2bfbits(acc);
}

__global__ void agg_gemm_ln_kernel(const unsigned short* __restrict__ Xs,
                                   const int* __restrict__ row_beg, const int* __restrict__ cnt,
                                   const int* __restrict__ col, const float* __restrict__ dinv,
                                   const float* __restrict__ W, const float* __restrict__ b,
                                   const float* __restrict__ g, const float* __restrict__ be,
                                   const int* __restrict__ flag, void* __restrict__ out, int n) {
    __shared__ float Wl[D * D];
    int t = threadIdx.x;
    for (int i = t; i < D * D; i += 256) Wl[i] = W[i];
    __syncthreads();
    int node = blockIdx.x * 4 + (t >> 6);
    int lane = t & 63;
    if (node >= n) return;
    float x8[8];
    aggregate8(Xs, row_beg, cnt, col, dinv, node, lane, x8);
    float acc = 0.f;
#pragma unroll
    for (int k = 0; k < D; ++k) {
        float xv = __shfl(x8[k & 7], k >> 3, 64);
        acc = fmaf(xv, Wl[k * D + lane], acc);
    }
    acc += b[lane];
    float s = acc;
#pragma unroll
    for (int off = 32; off > 0; off >>= 1) s += __shfl_xor(s, off, 64);
    float mu  = s * (1.f / 64.f);
    float dfe = acc - mu;
    float v   = dfe * dfe;
#pragma unroll
    for (int off = 32; off > 0; off >>= 1) v += __shfl_xor(v, off, 64);
    float var = v * (1.f / 64.f);
    float r   = rsqrtf(var + 1e-5f);
    float o   = dfe * r * g[lane] + be[lane];
    size_t oi = (size_t)node * D + lane;
    if (*flag) ((float*)out)[oi] = o;
    else       ((unsigned short*)out)[oi] = f2bfbits(o);
}

// ---- driver ----------------------------------------------------------------

extern "C" void kernel_launch(void* const* d_in, const int* in_sizes, int n_in,
                              void* d_out, int out_size, void* d_ws, size_t ws_size,
                              hipStream_t stream) {
    const void* X   = d_in[0];
    const void* W1  = d_in[1];
    const void* b1  = d_in[2];
    const void* W2  = d_in[3];
    const void* b2  = d_in[4];
    const void* W3  = d_in[5];
    const void* b3  = d_in[6];
    const void* pa  = d_in[7];
    const void* g   = d_in[8];
    const void* be  = d_in[9];
    const int*  ei  = (const int*)d_in[10];

    int N = in_sizes[0] / D;
    int E = in_sizes[10] / 2;
    int NB = (N + 63) >> BK_SHIFT;   // <= 1024 for N <= 65536
    int CH = (E + NBLK - 1) / NBLK;  // edges per radix block
    const int* src = ei;
    const int* dst = ei + E;

    char* p = (char*)d_ws;
    auto alloc = [&](size_t bytes) { void* q = (void*)p; p += (bytes + 255) & ~(size_t)255; return q; };
    int*            flag       = (int*)alloc(4);
    int*            H          = (int*)alloc((size_t)1024 * NBLK * 4);
    int*            T          = (int*)alloc(1024 * 4);
    int*            bucket_beg = (int*)alloc(1025 * 4);
    int*            row_beg    = (int*)alloc((size_t)N * 4);
    int*            cnt        = (int*)alloc((size_t)N * 4);
    float*          dinv       = (float*)alloc((size_t)N * 4);
    int*            col        = (int*)alloc((size_t)E * 4);
    unsigned int*   tmp        = (unsigned int*)alloc((size_t)E * 4);
    float*          P          = (float*)alloc((size_t)(OPA + 1) * 4);
    unsigned short* Xs         = (unsigned short*)alloc((size_t)N * D * 2);
    unsigned short* Xs2        = (unsigned short*)alloc((size_t)N * D * 2);
    (void)ws_size; (void)n_in; (void)out_size;

    sniff_kernel<<<1, 64, 0, stream>>>((const unsigned short*)W1, flag);
    cvt_params_kernel<<<1, 256, 0, stream>>>(W1, b1, W2, b2, W3, b3, pa, g, be, flag, P);

    binA1_kernel<<<NBLK, 256, 0, stream>>>(dst, E, NB, CH, H);
    binA2_kernel<<<NB, 256, 0, stream>>>(H, T);
    binA3_kernel<<<1, 1024, 0, stream>>>(T, bucket_beg, NB);
    binA4_kernel<<<NBLK, 256, 0, stream>>>(src, dst, H, bucket_beg, tmp, E, NB, CH);
    binB_kernel<<<NB, 256, 0, stream>>>(tmp, bucket_beg, row_beg, cnt, dinv, col, N);

    int nwb = (N * D + 255) / 256;   // one wave per node
    int ngb = (N + 3) / 4;           // 4 nodes per 256-thread block

    prescale_kernel<<<nwb, 256, 0, stream>>>(X, dinv, flag, Xs, N);

    agg_gemm_kernel   <<<ngb, 256, 0, stream>>>(Xs,  row_beg, cnt, col, dinv, P + OW1, P + OB1, P + OPA, Xs2, N);
    agg_gemm_kernel   <<<ngb, 256, 0, stream>>>(Xs2, row_beg, cnt, col, dinv, P + OW2, P + OB2, P + OPA, Xs,  N);
    agg_gemm_ln_kernel<<<ngb, 256, 0, stream>>>(Xs,  row_beg, cnt, col, dinv, P + OW3, P + OB3, P + OG, P + OBE, flag, d_out, N);
}